// Round 1
// baseline (354.269 us; speedup 1.0000x reference)
//
#include <hip/hip_runtime.h>

// ---------------------------------------------------------------------------
// Fused 4-expert MoE actor:  gate(softmax) -> L1(relu) -> L2(relu) -> head
// Trick: blend commutes into GEMM:  sum_e c_e (x@W_e) = [c_e*x]_cat @ vstack(W_e)
// All GEMMs on v_mfma_f32_16x16x32_f16, fp32 accum. Weights pre-converted to
// f16 in d_ws by a prep kernel, laid out in exact MFMA B-fragment order so the
// main kernel stages them with global_load_lds dwordx4 (no transpose/VALU).
// ---------------------------------------------------------------------------

typedef _Float16 half8 __attribute__((ext_vector_type(8)));
typedef _Float16 half4v __attribute__((ext_vector_type(4)));
typedef float floatx4 __attribute__((ext_vector_type(4)));

#define MFMA16(a, b, c) __builtin_amdgcn_mfma_f32_16x16x32_f16(a, b, c, 0, 0, 0)
#define WAIT_VM(N) asm volatile("s_waitcnt vmcnt(" #N ")" ::: "memory")
#define WAIT_LGKM0 asm volatile("s_waitcnt lgkmcnt(0)" ::: "memory")

__device__ __forceinline__ void barrier_mem() {
  asm volatile("" ::: "memory");
  __builtin_amdgcn_s_barrier();
  asm volatile("" ::: "memory");
}

__device__ __forceinline__ half8 splat8(_Float16 v) {
  half8 r = {v, v, v, v, v, v, v, v};
  return r;
}

// global -> LDS direct copy, 16B per lane. LDS dest is wave-uniform base
// (HW adds lane*16); global src is per-lane (must include lane*8 halfwords).
__device__ __forceinline__ void load_lds16(const _Float16* g, _Float16* s) {
  __builtin_amdgcn_global_load_lds((__attribute__((address_space(1))) void*)(g),
                                   (__attribute__((address_space(3))) void*)(s), 16, 0, 0);
}

// ---- d_ws halfword offsets (prepped f16 weights in fragment order) ----
enum {
  W1P = 0,            // 32 ksteps x [16 ct][64 l][8 j]            = 262144
  W2P = 262144,       // 32 ksteps x [ 8 ct][64 l][8 j]            = 131072
  WMUP = 393216,      // 16 ksteps x [ 2 ct][64 l][8 j] (pad N=32) =  16384
  GW1P = 409600,      //  8 ksteps x [ 2 ct][64 l][8 j]            =   8192
  GW2P = 417792,      //  1 kstep  x [ 2 ct][64 l][8 j]            =   1024
  B1P = 418816,       //  [16 ct][64 l][8 j], k<4 = b1             =   8192
  B2P = 427008,       //  [ 8 ct][64 l][8 j], k<4 = b2             =   4096
  BMUP = 431104,      //  [ 2 ct][64 l][8 j], k<4,o<17 = bmu       =   1024
  WS_TOTAL = 432128
};

__global__ __launch_bounds__(256) void prep_kernel(
    const float* __restrict__ W1, const float* __restrict__ W2,
    const float* __restrict__ Wmu, const float* __restrict__ gW1,
    const float* __restrict__ gW2, const float* __restrict__ b1,
    const float* __restrict__ b2, const float* __restrict__ bmu,
    _Float16* __restrict__ ws) {
  int p = blockIdx.x * 256 + threadIdx.x;
  if (p >= WS_TOTAL) return;
  float v = 0.f;
  if (p < W2P) {  // W1 stacked [1024 k][256 o]
    int q = p, ks = q >> 13, r = q & 8191, ct = r >> 9, l = (r >> 3) & 63, j = r & 7;
    int k = ks * 32 + ((l >> 4) << 3) + j, o = (ct << 4) + (l & 15);
    v = W1[k * 256 + o];  // [e][i][o] contiguous == [1024][256]
  } else if (p < WMUP) {  // W2 stacked [1024 k][128 o]
    int q = p - W2P, ks = q >> 12, r = q & 4095, ct = r >> 9, l = (r >> 3) & 63, j = r & 7;
    int k = ks * 32 + ((l >> 4) << 3) + j, o = (ct << 4) + (l & 15);
    v = W2[k * 128 + o];
  } else if (p < GW1P) {  // Wmu stacked [512 k][17 o] padded to 32 cols
    int q = p - WMUP, ks = q >> 10, r = q & 1023, ct = r >> 9, l = (r >> 3) & 63, j = r & 7;
    int k = ks * 32 + ((l >> 4) << 3) + j, o = (ct << 4) + (l & 15);
    v = (o < 17) ? Wmu[k * 17 + o] : 0.f;
  } else if (p < GW2P) {  // gW1 [256][32]
    int q = p - GW1P, ks = q >> 10, r = q & 1023, ct = r >> 9, l = (r >> 3) & 63, j = r & 7;
    int k = ks * 32 + ((l >> 4) << 3) + j, o = (ct << 4) + (l & 15);
    v = gW1[k * 32 + o];
  } else if (p < B1P) {  // gW2 [32][32]
    int q = p - GW2P, ct = q >> 9, l = (q >> 3) & 63, j = q & 7;
    int k = ((l >> 4) << 3) + j, o = (ct << 4) + (l & 15);
    v = gW2[k * 32 + o];
  } else if (p < B2P) {  // b1 [4][256] as K=32 bias tile
    int q = p - B1P, ct = q >> 9, l = (q >> 3) & 63, j = q & 7;
    int k = ((l >> 4) << 3) + j, o = (ct << 4) + (l & 15);
    v = (k < 4) ? b1[k * 256 + o] : 0.f;
  } else if (p < BMUP) {  // b2 [4][128]
    int q = p - B2P, ct = q >> 9, l = (q >> 3) & 63, j = q & 7;
    int k = ((l >> 4) << 3) + j, o = (ct << 4) + (l & 15);
    v = (k < 4) ? b2[k * 128 + o] : 0.f;
  } else {  // bmu [4][17]
    int q = p - BMUP, ct = q >> 9, l = (q >> 3) & 63, j = q & 7;
    int k = ((l >> 4) << 3) + j, o = (ct << 4) + (l & 15);
    v = (k < 4 && o < 17) ? bmu[k * 17 + o] : 0.f;
  }
  ws[p] = (_Float16)v;
}

// LDS layout (halfwords). x tile stride 264 = 16B*33: b128-aligned, odd 16B
// stride -> bank-quads balanced (floor-rate ds_read_b128).
enum { XS = 264, X_HW = 128 * XS, STG_HW = 3 * 8192, CP_OFF = X_HW + STG_HW, LDS_HW = CP_OFF + 128 * 32 };

__global__ __launch_bounds__(512, 2) void actor_kernel(
    const float* __restrict__ x, const _Float16* __restrict__ ws,
    const float* __restrict__ gb1, const float* __restrict__ gb2,
    const float* __restrict__ gWo, const float* __restrict__ gbo,
    float* __restrict__ out) {
  __shared__ __align__(16) _Float16 lds[LDS_HW];
  _Float16* xl = lds;            // x f16 [128][264]; reused for h1 [128][264], h2 [128][136]
  _Float16* stg = lds + X_HW;    // 3 x 16KB stage buffers
  _Float16* cp = lds + CP_OFF;   // c padded [128][32] f16 (softmax coeffs, cols>=4 zero)

  const int tid = threadIdx.x;
  const int l = tid & 63;
  const int w = tid >> 6;
  const int l15 = l & 15;
  const int g8 = (l >> 4) << 3;       // k sub-offset of this lane's fragment
  const int wrow16 = w * 16;          // gate/head row base (8 waves x 16 rows)
  const int wr = (w >> 2) * 64;       // layer1/2 wave row base (2x4 wave grid)
  const int wc1 = (w & 3) * 64;       // layer1 wave col base
  const int wc2 = (w & 3) * 32;       // layer2 wave col base
  const long rowbase = (long)blockIdx.x * 128;

  // ---------------- phase 0: x -> LDS (f16) + stage gate weights ------------
  {
    const float* xp = x + rowbase * 256;
#pragma unroll 4
    for (int it = 0; it < 16; ++it) {
      int row = w + it * 8;
      int c4 = (l)*4;
      float4 v = *(const float4*)(xp + row * 256 + c4);
      half4v h = {(_Float16)v.x, (_Float16)v.y, (_Float16)v.z, (_Float16)v.w};
      *(half4v*)(&xl[row * XS + c4]) = h;
    }
    for (int i = w; i < 16; i += 8) load_lds16(ws + GW1P + i * 512 + l * 8, stg + i * 512);          // gW1p -> buf0
    for (int i = w; i < 2; i += 8) load_lds16(ws + GW2P + i * 512 + l * 8, stg + 8192 + i * 512);    // gW2p -> buf1
    WAIT_VM(0);
    WAIT_LGKM0;
    barrier_mem();
  }

  // ---------------- gate GEMM1: [128,256]@[256,32], elu -> g1 (buf2) --------
  {
    const floatx4 z4 = {0.f, 0.f, 0.f, 0.f};
    floatx4 ga[2] = {z4, z4};
#pragma unroll
    for (int ks = 0; ks < 8; ++ks) {
      half8 a = *(const half8*)(&xl[(wrow16 + l15) * XS + ks * 32 + g8]);
#pragma unroll
      for (int ct = 0; ct < 2; ++ct) {
        half8 b = *(const half8*)(&stg[ks * 1024 + ct * 512 + l * 8]);
        ga[ct] = MFMA16(a, b, ga[ct]);
      }
    }
#pragma unroll
    for (int ct = 0; ct < 2; ++ct) {
      int col = ct * 16 + l15;
      float bias = gb1[col];
#pragma unroll
      for (int rg = 0; rg < 4; ++rg) {
        int row = wrow16 + ((l >> 4) << 2) + rg;
        float v = ga[ct][rg] + bias;
        v = (v > 0.f) ? v : (__expf(v) - 1.f);
        stg[16384 + row * 40 + col] = (_Float16)v;  // g1 in buf2, [128][40]
      }
    }
    WAIT_LGKM0;
    barrier_mem();
  }

  // ---------------- gate GEMM2: [128,32]@[32,32], elu -> g2 (buf0) ----------
  {
    const floatx4 z4 = {0.f, 0.f, 0.f, 0.f};
    floatx4 ga[2] = {z4, z4};
    half8 a = *(const half8*)(&stg[16384 + (wrow16 + l15) * 40 + g8]);
#pragma unroll
    for (int ct = 0; ct < 2; ++ct) {
      half8 b = *(const half8*)(&stg[8192 + ct * 512 + l * 8]);
      ga[ct] = MFMA16(a, b, ga[ct]);
    }
#pragma unroll
    for (int ct = 0; ct < 2; ++ct) {
      int col = ct * 16 + l15;
      float bias = gb2[col];
#pragma unroll
      for (int rg = 0; rg < 4; ++rg) {
        int row = wrow16 + ((l >> 4) << 2) + rg;
        float v = ga[ct][rg] + bias;
        v = (v > 0.f) ? v : (__expf(v) - 1.f);
        stg[row * 40 + col] = (_Float16)v;  // g2 in buf0, [128][40]
      }
    }
    WAIT_LGKM0;
    barrier_mem();
  }

  // ---------------- logits: [128,32]@[32,4] (VALU) -> buf1 ------------------
  {
    int row = tid >> 2, e = tid & 3;
    float s = gbo[e];
#pragma unroll
    for (int i8 = 0; i8 < 4; ++i8) {
      half8 gv = *(const half8*)(&stg[row * 40 + i8 * 8]);
#pragma unroll
      for (int j = 0; j < 8; ++j) s += (float)gv[j] * gWo[(i8 * 8 + j) * 4 + e];
    }
    ((float*)(stg + 8192))[row * 4 + e] = s;
    WAIT_LGKM0;
    barrier_mem();
  }

  // ---------------- softmax -> cp (c padded [128][32]); stage b1p -> buf0 ---
  if (tid < 128) {
    const float* lg = (const float*)(stg + 8192) + tid * 4;
    float m0 = fmaxf(fmaxf(lg[0], lg[1]), fmaxf(lg[2], lg[3]));
    float e0 = __expf(lg[0] - m0), e1 = __expf(lg[1] - m0);
    float e2 = __expf(lg[2] - m0), e3 = __expf(lg[3] - m0);
    float inv = 1.f / (e0 + e1 + e2 + e3);
    _Float16* cr = &cp[tid * 32];
    cr[0] = (_Float16)(e0 * inv);
    cr[1] = (_Float16)(e1 * inv);
    cr[2] = (_Float16)(e2 * inv);
    cr[3] = (_Float16)(e3 * inv);
#pragma unroll
    for (int z = 4; z < 32; ++z) cr[z] = (_Float16)0.f;
  }
  for (int i = w; i < 16; i += 8) load_lds16(ws + B1P + i * 512 + l * 8, stg + i * 512);  // b1p -> buf0
  WAIT_LGKM0;
  barrier_mem();

  // ---------------- per-lane coeff preload + stage W1p ks0 -> buf1 ----------
  _Float16 c16[4][4];
#pragma unroll
  for (int rt = 0; rt < 4; ++rt)
#pragma unroll
    for (int e = 0; e < 4; ++e) c16[rt][e] = cp[(wr + rt * 16 + l15) * 32 + e];
  for (int i = w; i < 16; i += 8) load_lds16(ws + W1P + i * 512 + l * 8, stg + 8192 + i * 512);
  WAIT_VM(2);  // b1p landed; W1p ks0 (2 insts) in flight
  barrier_mem();

  // ---------------- layer 1: [128,1024]@[1024,256] + blended bias, relu ----
  floatx4 acc[4][4];
  {  // t=0: accumulator init = bias blend:  cp @ b1p
    const floatx4 z4 = {0.f, 0.f, 0.f, 0.f};
#pragma unroll
    for (int rt = 0; rt < 4; ++rt) {
      half8 a = *(const half8*)(&cp[(wr + rt * 16 + l15) * 32 + g8]);
#pragma unroll
      for (int ct = 0; ct < 4; ++ct) {
        half8 b = *(const half8*)(&stg[((w & 3) * 4 + ct) * 512 + l * 8]);
        acc[rt][ct] = MFMA16(a, b, z4);
      }
    }
  }
  for (int i = w; i < 16; i += 8) load_lds16(ws + W1P + 8192 + i * 512 + l * 8, stg + 16384 + i * 512);  // t2

#pragma unroll
  for (int e = 0; e < 4; ++e) {
    const half8 cs[4] = {splat8(c16[0][e]), splat8(c16[1][e]), splat8(c16[2][e]), splat8(c16[3][e])};
#pragma unroll 1
    for (int t8 = 0; t8 < 8; ++t8) {
      const int t = e * 8 + t8 + 1;  // tile 1..32, kstep ks = t-1
      if (t == 32) { WAIT_VM(0); } else { WAIT_VM(2); }
      barrier_mem();
      const int xk = t8 << 5;
      const _Float16* bb = stg + (t % 3) * 8192;
      half8 a[4];
#pragma unroll
      for (int rt = 0; rt < 4; ++rt) {
        half8 raw = *(const half8*)(&xl[(wr + rt * 16 + l15) * XS + xk + g8]);
        a[rt] = raw * cs[rt];
      }
#pragma unroll
      for (int ct = 0; ct < 4; ++ct) {
        half8 b = *(const half8*)(&bb[((w & 3) * 4 + ct) * 512 + l * 8]);
#pragma unroll
        for (int rt = 0; rt < 4; ++rt) acc[rt][ct] = MFMA16(a[rt], b, acc[rt][ct]);
      }
      if (t <= 30) {
        const _Float16* src = ws + W1P + (t + 1) * 8192;
        _Float16* dst = stg + ((t + 2) % 3) * 8192;
        for (int i = w; i < 16; i += 8) load_lds16(src + i * 512 + l * 8, dst + i * 512);
      }
    }
  }
  barrier_mem();  // all reads of xl done -> safe to overwrite with h1

  // h1 = relu(acc) -> xl [128][264]
#pragma unroll
  for (int rt = 0; rt < 4; ++rt)
#pragma unroll
    for (int ct = 0; ct < 4; ++ct) {
      int col = wc1 + ct * 16 + l15;
#pragma unroll
      for (int rg = 0; rg < 4; ++rg) {
        int row = wr + rt * 16 + ((l >> 4) << 2) + rg;
        float v = acc[rt][ct][rg];
        xl[row * XS + col] = (_Float16)(v > 0.f ? v : 0.f);
      }
    }
  for (int i = w; i < 8; i += 8) load_lds16(ws + B2P + i * 512 + l * 8, stg + i * 512);  // b2p -> buf0
  WAIT_LGKM0;
  barrier_mem();
  for (int i = w; i < 8; i += 8) load_lds16(ws + W2P + i * 512 + l * 8, stg + 8192 + i * 512);  // t1
  WAIT_VM(1);
  barrier_mem();

  // ---------------- layer 2: [128,1024]@[1024,128] + blended bias, relu ----
  floatx4 acc2[4][2];
  {
    const floatx4 z4 = {0.f, 0.f, 0.f, 0.f};
#pragma unroll
    for (int rt = 0; rt < 4; ++rt) {
      half8 a = *(const half8*)(&cp[(wr + rt * 16 + l15) * 32 + g8]);
#pragma unroll
      for (int ct = 0; ct < 2; ++ct) {
        half8 b = *(const half8*)(&stg[((w & 3) * 2 + ct) * 512 + l * 8]);
        acc2[rt][ct] = MFMA16(a, b, z4);
      }
    }
  }
  for (int i = w; i < 8; i += 8) load_lds16(ws + W2P + 4096 + i * 512 + l * 8, stg + 16384 + i * 512);  // t2

#pragma unroll
  for (int e = 0; e < 4; ++e) {
    const half8 cs[4] = {splat8(c16[0][e]), splat8(c16[1][e]), splat8(c16[2][e]), splat8(c16[3][e])};
#pragma unroll 1
    for (int t8 = 0; t8 < 8; ++t8) {
      const int t = e * 8 + t8 + 1;
      if (t == 32) { WAIT_VM(0); } else { WAIT_VM(1); }
      barrier_mem();
      const int xk = t8 << 5;
      const _Float16* bb = stg + (t % 3) * 8192;
      half8 a[4];
#pragma unroll
      for (int rt = 0; rt < 4; ++rt) {
        half8 raw = *(const half8*)(&xl[(wr + rt * 16 + l15) * XS + xk + g8]);
        a[rt] = raw * cs[rt];
      }
#pragma unroll
      for (int ct = 0; ct < 2; ++ct) {
        half8 b = *(const half8*)(&bb[((w & 3) * 2 + ct) * 512 + l * 8]);
#pragma unroll
        for (int rt = 0; rt < 4; ++rt) acc2[rt][ct] = MFMA16(a[rt], b, acc2[rt][ct]);
      }
      if (t <= 30) {
        const _Float16* src = ws + W2P + (t + 1) * 4096;
        _Float16* dst = stg + ((t + 2) % 3) * 8192;
        for (int i = w; i < 8; i += 8) load_lds16(src + i * 512 + l * 8, dst + i * 512);
      }
    }
  }
  barrier_mem();  // all reads of h1 done

  // h2 = relu(acc2) -> xl as [128][136]
#pragma unroll
  for (int rt = 0; rt < 4; ++rt)
#pragma unroll
    for (int ct = 0; ct < 2; ++ct) {
      int col = wc2 + ct * 16 + l15;
#pragma unroll
      for (int rg = 0; rg < 4; ++rg) {
        int row = wr + rt * 16 + ((l >> 4) << 2) + rg;
        float v = acc2[rt][ct][rg];
        xl[row * 136 + col] = (_Float16)(v > 0.f ? v : 0.f);
      }
    }
  // stage head: tile0 = bmup, tiles 1..16 = Wmup ksteps (2 chunks each)
  for (int i = w; i < 34; i += 8) {
    int tile = i >> 1, half = i & 1;
    const _Float16* src = ws + (tile == 0 ? BMUP : WMUP + (tile - 1) * 1024) + half * 512 + l * 8;
    load_lds16(src, stg + i * 512);
  }
  WAIT_LGKM0;
  WAIT_VM(0);
  barrier_mem();

  // ---------------- head: [128,512]@[512,32(pad)] + blended bias -----------
  floatx4 hacc[2];
  {
    const floatx4 z4 = {0.f, 0.f, 0.f, 0.f};
    half8 a = *(const half8*)(&cp[(wrow16 + l15) * 32 + g8]);
#pragma unroll
    for (int ct = 0; ct < 2; ++ct) {
      half8 b = *(const half8*)(&stg[ct * 512 + l * 8]);
      hacc[ct] = MFMA16(a, b, z4);
    }
  }
#pragma unroll
  for (int ksv = 0; ksv < 16; ++ksv) {
    const int e = ksv >> 2;
    const int xk = (ksv & 3) << 5;
    half8 raw = *(const half8*)(&xl[(wrow16 + l15) * 136 + xk + g8]);
    half8 a = raw * splat8(c16[w & 3][e]);  // head row w*16+(l&15) == wr+(w&3)*16+(l&15)
#pragma unroll
    for (int ct = 0; ct < 2; ++ct) {
      half8 b = *(const half8*)(&stg[(ksv + 1) * 1024 + ct * 512 + l * 8]);
      hacc[ct] = MFMA16(a, b, hacc[ct]);
    }
  }
  // store mu [128][17] f32 (no activation)
#pragma unroll
  for (int ct = 0; ct < 2; ++ct) {
    int col = ct * 16 + l15;
    if (col < 17) {
#pragma unroll
      for (int rg = 0; rg < 4; ++rg) {
        int row = wrow16 + ((l >> 4) << 2) + rg;
        out[(rowbase + row) * 17 + col] = hacc[ct][rg];
      }
    }
  }
}

extern "C" void kernel_launch(void* const* d_in, const int* in_sizes, int n_in,
                              void* d_out, int out_size, void* d_ws, size_t ws_size,
                              hipStream_t stream) {
  const float* x = (const float*)d_in[0];
  const float* W1 = (const float*)d_in[1];
  const float* b1 = (const float*)d_in[2];
  const float* W2 = (const float*)d_in[3];
  const float* b2 = (const float*)d_in[4];
  const float* Wmu = (const float*)d_in[5];
  const float* bmu = (const float*)d_in[6];
  const float* gW1 = (const float*)d_in[7];
  const float* gb1 = (const float*)d_in[8];
  const float* gW2 = (const float*)d_in[9];
  const float* gb2 = (const float*)d_in[10];
  const float* gWo = (const float*)d_in[11];
  const float* gbo = (const float*)d_in[12];
  float* out = (float*)d_out;
  _Float16* ws = (_Float16*)d_ws;

  prep_kernel<<<(WS_TOTAL + 255) / 256, 256, 0, stream>>>(W1, W2, Wmu, gW1, gW2, b1, b2, bmu, ws);
  actor_kernel<<<1024, 512, 0, stream>>>(x, ws, gb1, gb2, gWo, gbo, out);
}